// Round 12
// baseline (218.000 us; speedup 1.0000x reference)
//
#include <hip/hip_runtime.h>
#include <math.h>

// ---------------- LDS layout (floats), per 64-thread (1-wave) block ----------
// TWO samples per wave (A/B), disjoint zones, chains interleaved for ILP.
#define WC3   0      // l1c3 [q3][m4][n4][q4]            128
#define WC2   128    // l1c2 [q2][m3][n3][q3]            128
#define WU1   256    // l2c1                              32  -> 288
#define T2A_  288    // A: T2 [32][36] = 1152                 -> 1440
#define T3A_  1440   // A: T3 [32][34] = 1088                 -> 2528
#define T2B_  2528   // B: T2                                 -> 3680
#define T3B_  3680   // B: T3                                 -> 4768
#define H1A_  288    // h1 A (2048) overlays A zone           -> 2336
#define H1B_  2528   // h1 B overlays B zone                  -> 4576
#define BO_A  4768   // B[128][9] = 1152                      -> 5920
#define BO_B  5920   //                                       -> 7072
#define CO_A  7072   // C[32][17] = 544                       -> 7616
#define CO_B  7616   //                                       -> 8160
#define DO_A  8160   // D[16][17] = 272                       -> 8432
#define DO_B  8432   //                                       -> 8704
#define H2A_  8704   // 64                                    -> 8768
#define H2B_  8768   //                                       -> 8832
#define H3A_  8832   // 32                                    -> 8864
#define H3B_  8864   //                                       -> 8896
#define LDS_FLOATS 8896   // 35584 B -> 4 blocks/CU (grid 1024 = 4 blocks/CU)

// Setup: dense layer-3 matrix W3[mi(32)][nj(64)] from TT cores (tiny).
__global__ void tt_setup_w3(const float* __restrict__ v0, const float* __restrict__ v1,
                            const float* __restrict__ v2, const float* __restrict__ v3,
                            const float* __restrict__ v4, float* __restrict__ w3) {
    int i = blockIdx.x * 256 + threadIdx.x;
    if (i >= 2048) return;
    int mi = i >> 6, nj = i & 63;
    int m1 = (mi >> 4) & 1, m2 = (mi >> 3) & 1, m3 = (mi >> 2) & 1, m4 = (mi >> 1) & 1, m5 = mi & 1;
    int n1 = (nj >> 4) & 3, n2 = (nj >> 3) & 1, n3 = (nj >> 2) & 1, n4 = (nj >> 1) & 1, n5 = nj & 1;
    float s = 0.f;
#pragma unroll
    for (int q1 = 0; q1 < 2; ++q1) {
        float a1 = v0[(m1 * 4 + n1) * 2 + q1];
#pragma unroll
        for (int q2 = 0; q2 < 2; ++q2) {
            float a2 = a1 * v1[((q1 * 2 + m2) * 2 + n2) * 2 + q2];
#pragma unroll
            for (int q3 = 0; q3 < 2; ++q3) {
                float a3 = a2 * v2[((q2 * 2 + m3) * 2 + n3) * 2 + q3];
#pragma unroll
                for (int q4 = 0; q4 < 2; ++q4)
                    s = fmaf(a3 * v3[((q3 * 2 + m4) * 2 + n4) * 2 + q4],
                             v4[(q4 * 2 + m5) * 2 + n5], s);
            }
        }
    }
    w3[i] = s;
}

// ---- per-sample step macros (all register indices compile-time; rule #20;
//      runtime values appear only in LDS/global addresses) ----
#define PREFETCH_X(BUF, XB, SLAB) do {                                      \
    const float4* xq_ = (const float4*)(XB) + (SLAB) * 512 + t * 8;         \
    _Pragma("unroll") for (int i_ = 0; i_ < 8; ++i_) {                      \
        const float4 v_ = xq_[i_];                                          \
        BUF[i_*4+0] = v_.x; BUF[i_*4+1] = v_.y;                             \
        BUF[i_*4+2] = v_.z; BUF[i_*4+3] = v_.w;                             \
    } } while (0)

#define STEP1(T1, BUF) do {                                                 \
    _Pragma("unroll") for (int m5_ = 0; m5_ < 4; ++m5_)                     \
    _Pragma("unroll") for (int q4_ = 0; q4_ < 2; ++q4_) {                   \
        const float* w_ = g4 + (q4_ * 4 + m5_) * 8;                         \
        _Pragma("unroll") for (int n4l_ = 0; n4l_ < 4; ++n4l_) {            \
            float sa_ = BUF[n4l_*8+0] * w_[0];                              \
            _Pragma("unroll") for (int n5_ = 1; n5_ < 8; ++n5_)             \
                sa_ = fmaf(BUF[n4l_*8+n5_], w_[n5_], sa_);                  \
            T1[n4l_*8 + m5_*2 + q4_] = sa_;                                 \
        } } } while (0)

#define STEP2(ACC, T1) do {                                                 \
    _Pragma("unroll") for (int i_ = 0; i_ < 16; ++i_) ACC[i_] = 0.f;        \
    _Pragma("unroll") for (int pass_ = 0; pass_ < 2; ++pass_) {             \
        const int hh_ = (pass_ == 0) ? h : (1 - h);                         \
        if (pass_ == 1) {                                                   \
            _Pragma("unroll") for (int i_ = 0; i_ < 32; ++i_)               \
                T1[i_] = __shfl_xor(T1[i_], 1);                             \
        }                                                                   \
        _Pragma("unroll") for (int m4_ = 0; m4_ < 4; ++m4_) {               \
            const int cb_ = WC3 + ((h * 4 + m4_) * 8 + hh_ * 4) * 2;        \
            const float4 c0_ = *(const float4*)&smem[cb_];                  \
            const float4 c1_ = *(const float4*)&smem[cb_ + 4];              \
            const float cs_[8] = {c0_.x,c0_.y,c0_.z,c0_.w,c1_.x,c1_.y,c1_.z,c1_.w}; \
            _Pragma("unroll") for (int m5_ = 0; m5_ < 4; ++m5_) {           \
                float sa_ = ACC[m4_*4+m5_];                                 \
                _Pragma("unroll") for (int n4l_ = 0; n4l_ < 4; ++n4l_)      \
                _Pragma("unroll") for (int q4_ = 0; q4_ < 2; ++q4_)         \
                    sa_ = fmaf(T1[n4l_*8 + m5_*2 + q4_], cs_[n4l_*2+q4_], sa_); \
                ACC[m4_*4+m5_] = sa_;                                       \
            } } } } while (0)

#define STEP3(T2X, T3X) do {                                                \
    const int n3h_ = t & 1, q2_ = (t >> 1) & 1, m3_ = (t >> 2) & 3, n2l_ = t >> 4; \
    float o3_[16];                                                          \
    _Pragma("unroll") for (int i_ = 0; i_ < 16; ++i_) o3_[i_] = 0.f;        \
    _Pragma("unroll") for (int n3l_ = 0; n3l_ < 4; ++n3l_) {                \
        const int rb_ = (T2X) + (n2l_*8 + n3h_*4 + n3l_) * 36;              \
        float rv_[32];                                                      \
        _Pragma("unroll") for (int g_ = 0; g_ < 8; ++g_) {                  \
            const float4 v_ = *(const float4*)&smem[rb_ + g_*4];            \
            rv_[g_*4+0]=v_.x; rv_[g_*4+1]=v_.y; rv_[g_*4+2]=v_.z; rv_[g_*4+3]=v_.w; \
        }                                                                   \
        const int wb_ = WC2 + ((q2_*4 + m3_)*8 + n3h_*4 + n3l_) * 2;        \
        const float w0_ = smem[wb_], w1_ = smem[wb_+1];                     \
        _Pragma("unroll") for (int m45_ = 0; m45_ < 16; ++m45_)             \
            o3_[m45_] = fmaf(rv_[m45_*2], w0_, fmaf(rv_[m45_*2+1], w1_, o3_[m45_])); \
    }                                                                       \
    _Pragma("unroll") for (int k_ = 0; k_ < 16; ++k_) o3_[k_] += __shfl_xor(o3_[k_], 1); \
    const int row_ = n2h*16 + n2l_*4 + m3_;                                 \
    _Pragma("unroll") for (int k_ = 0; k_ < 8; ++k_) {                      \
        const float v_ = n3h_ ? o3_[8+k_] : o3_[k_];                        \
        smem[(T3X) + row_*34 + (n3h_*8+k_)*2 + q2_] = v_;                   \
    } } while (0)

#define STEP4(T3X, RT4) do {                                                \
    const int m3_ = t >> 4, m4_ = (t >> 2) & 3, m5_ = t & 3;                \
    float2 zz_[8];                                                          \
    _Pragma("unroll") for (int n2_ = 0; n2_ < 8; ++n2_)                     \
        zz_[n2_] = *(const float2*)&smem[(T3X) + (n2_*4+m3_)*34 + (m4_*4+m5_)*2]; \
    _Pragma("unroll") for (int jj_ = 0; jj_ < 4; ++jj_)                     \
    _Pragma("unroll") for (int q1_ = 0; q1_ < 3; ++q1_) {                   \
        float sa_ = RT4[jj_*9 + n1*3 + q1_];                                \
        _Pragma("unroll") for (int n2g_ = 0; n2g_ < 4; ++n2g_) {            \
            const float4 w_ = *(const float4*)(g1 + ((q1_*4+jj_)*8 + n2g_*2)*2); \
            sa_ = fmaf(zz_[n2g_*2].x,   w_.x, sa_);                         \
            sa_ = fmaf(zz_[n2g_*2].y,   w_.y, sa_);                         \
            sa_ = fmaf(zz_[n2g_*2+1].x, w_.z, sa_);                         \
            sa_ = fmaf(zz_[n2g_*2+1].y, w_.w, sa_);                         \
        }                                                                   \
        RT4[jj_*9 + n1*3 + q1_] = sa_;                                      \
    } } while (0)

#define L2AB(H1X, BOX) do {                                                 \
    _Pragma("unroll") for (int pq_ = 0; pq_ < 2; ++pq_) {                   \
        const int p3_ = 2*t + pq_;                                          \
        float o_[8];                                                        \
        _Pragma("unroll") for (int i_ = 0; i_ < 8; ++i_) o_[i_] = 0.f;      \
        _Pragma("unroll") for (int n4_ = 0; n4_ < 4; ++n4_) {               \
            const float4 hv_ = *(const float4*)&smem[(H1X) + (p3_*4+n4_)*4]; \
            const float ax_ = hv_.x*u4[0]  + hv_.y*u4[1]  + hv_.z*u4[2]  + hv_.w*u4[3];  \
            const float ay_ = hv_.x*u4[8]  + hv_.y*u4[9]  + hv_.z*u4[10] + hv_.w*u4[11]; \
            const float az_ = hv_.x*u4[4]  + hv_.y*u4[5]  + hv_.z*u4[6]  + hv_.w*u4[7];  \
            const float aw_ = hv_.x*u4[12] + hv_.y*u4[13] + hv_.z*u4[14] + hv_.w*u4[15]; \
            _Pragma("unroll") for (int q4_ = 0; q4_ < 2; ++q4_) {           \
                const float a0_ = q4_ ? ay_ : ax_;                          \
                const float a1_ = q4_ ? aw_ : az_;                          \
                _Pragma("unroll") for (int q3_ = 0; q3_ < 2; ++q3_)         \
                _Pragma("unroll") for (int m4_ = 0; m4_ < 2; ++m4_) {       \
                    const float w_ = u3[((q3_*2+m4_)*4+n4_)*2+q4_];         \
                    o_[(m4_*2+0)*2+q3_] = fmaf(a0_, w_, o_[(m4_*2+0)*2+q3_]); \
                    o_[(m4_*2+1)*2+q3_] = fmaf(a1_, w_, o_[(m4_*2+1)*2+q3_]); \
                } } }                                                       \
        _Pragma("unroll") for (int k_ = 0; k_ < 8; ++k_)                    \
            smem[(BOX) + p3_*9 + k_] = o_[k_];                              \
    } } while (0)

// Grid 1024 blocks x 64 threads: 4 waves/CU (1/SIMD). waves_per_eu(1,1):
// full 512-VGPR budget so the 2-sample live set (~210) fits spill-free.
// n2h loop is ROLLED (#pragma unroll 1) to keep code size ~R4-scale --
// the fully-unrolled R10 variant plausibly blew up compile time.
__global__ __launch_bounds__(64)
__attribute__((amdgpu_waves_per_eu(1, 1)))
void tt_main(const float* __restrict__ x,
             const float* __restrict__ g0, const float* __restrict__ g1,
             const float* __restrict__ g2, const float* __restrict__ g3,
             const float* __restrict__ g4, const float* __restrict__ b1g,
             const float* __restrict__ u0, const float* __restrict__ u1,
             const float* __restrict__ u2, const float* __restrict__ u3,
             const float* __restrict__ u4, const float* __restrict__ b2g,
             const float* __restrict__ b3g,
             const float* __restrict__ Wmg, const float* __restrict__ blg,
             const float* __restrict__ w3g,
             float* __restrict__ out)
{
    __shared__ float smem[LDS_FLOATS];
    const int t = threadIdx.x;
    const int b = blockIdx.x;
    const float* xbA = x + (size_t)(2 * b) * 12288;
    const float* xbB = xbA + 12288;

    // ---- issue x loads for both samples' slab 0 ----
    float xvA[32], xvB[32];
    PREFETCH_X(xvA, xbA, 0);
    PREFETCH_X(xvB, xbB, 0);

    // ---- non-uniformly-indexed weights to LDS ----
    smem[WC3 + t] = g3[t];  smem[WC3 + 64 + t] = g3[64 + t];
    smem[WC2 + t] = g2[t];  smem[WC2 + 64 + t] = g2[64 + t];
    if (t < 32) smem[WU1 + t] = u1[t];
    __syncthreads();  // weights ready

    const int h = t & 1;       // n4-half owned by this lane
    const int p = t >> 1;      // subslice-local prefix (n2l*8 + n3)

    float rT4A[36], rT4B[36];
#pragma unroll
    for (int i = 0; i < 36; ++i) { rT4A[i] = 0.f; rT4B[i] = 0.f; }

#pragma unroll
    for (int n1 = 0; n1 < 3; ++n1) {
#pragma unroll 1
        for (int n2h = 0; n2h < 2; ++n2h) {
            const int s = n1 * 2 + n2h;

            // step 1+2, chain A (t1 shared across chains: -32 peak regs)
            float t1[32];
            float accA[16], accB[16];
            STEP1(t1, xvA);
            if (s < 5) PREFETCH_X(xvA, xbA, s + 1);
            STEP2(accA, t1);

            // step 1+2, chain B
            STEP1(t1, xvB);
            if (s < 5) PREFETCH_X(xvB, xbB, s + 1);
            STEP2(accB, t1);

            __syncthreads();   // prior readers of T2/T3 zones done
#pragma unroll
            for (int m45 = 0; m45 < 16; ++m45)
                smem[T2A_ + p * 36 + m45 * 2 + h] = accA[m45];
#pragma unroll
            for (int m45 = 0; m45 < 16; ++m45)
                smem[T2B_ + p * 36 + m45 * 2 + h] = accB[m45];
            __syncthreads();   // T2s ready

            // step 3, both chains (disjoint zones; A's DS latency hides
            // under B's FMAs and vice versa -- the ILP payload)
            STEP3(T2A_, T3A_);
            STEP3(T2B_, T3B_);
        } // n2h
        __syncthreads();   // T3 complete for this n1

        // step 4, both chains (independent)
        STEP4(T3A_, rT4A);
        STEP4(T3B_, rT4B);
    } // n1
    __syncthreads();   // T3 reads done; h1 may overwrite zones

    // ---- step 5: contract n1,q1 + bias + relu -> h1 (bias shared A/B)
#pragma unroll
    for (int jj = 0; jj < 4; ++jj) {
        float bia[8];
#pragma unroll
        for (int m1 = 0; m1 < 8; ++m1) bia[m1] = b1g[m1 * 256 + jj * 64 + t];
#pragma unroll
        for (int m1 = 0; m1 < 8; ++m1) {
            float saA = bia[m1], saB = bia[m1];
#pragma unroll
            for (int n1 = 0; n1 < 3; ++n1)
#pragma unroll
            for (int q1 = 0; q1 < 3; ++q1) {
                const float w = g0[(m1 * 3 + n1) * 3 + q1];
                saA = fmaf(rT4A[jj * 9 + n1 * 3 + q1], w, saA);
                saB = fmaf(rT4B[jj * 9 + n1 * 3 + q1], w, saB);
            }
            smem[H1A_ + m1 * 256 + jj * 64 + t] = fmaxf(saA, 0.f);
            smem[H1B_ + m1 * 256 + jj * 64 + t] = fmaxf(saB, 0.f);
        }
    }
    __syncthreads();

    // ================= layer 2 (right-to-left) =================
    L2AB(H1A_, BO_A);
    L2AB(H1B_, BO_B);
    __syncthreads();

    // Tail stages: lanes 0-31 process sample A, lanes 32-63 sample B.
    const int sg = t >> 5;          // sample group
    const int tt = t & 31;          // lane within group
    const int BOS = sg ? BO_B : BO_A;
    const int COS = sg ? CO_B : CO_A;
    const int DOS = sg ? DO_B : DO_A;
    const int H2S = sg ? H2B_ : H2A_;
    const int H3S = sg ? H3B_ : H3A_;

    // L2c: contract n3(4),q3 -> C  (U2 uniform; all 64 lanes active)
    {
        float o[16];
#pragma unroll
        for (int i = 0; i < 16; ++i) o[i] = 0.f;
#pragma unroll
        for (int n3 = 0; n3 < 4; ++n3)
#pragma unroll
        for (int q3 = 0; q3 < 2; ++q3) {
            float zb[4];
#pragma unroll
            for (int m45 = 0; m45 < 4; ++m45)
                zb[m45] = smem[BOS + (tt * 4 + n3) * 9 + m45 * 2 + q3];
#pragma unroll
            for (int m3 = 0; m3 < 2; ++m3)
#pragma unroll
            for (int q2 = 0; q2 < 2; ++q2) {
                const float w = u2[((q2 * 2 + m3) * 4 + n3) * 2 + q3];
#pragma unroll
                for (int m45 = 0; m45 < 4; ++m45)
                    o[(m3 * 4 + m45) * 2 + q2] = fmaf(zb[m45], w, o[(m3 * 4 + m45) * 2 + q2]);
            }
        }
#pragma unroll
        for (int k = 0; k < 16; ++k) smem[COS + tt * 17 + k] = o[k];
    }
    __syncthreads();

    // L2d: contract n2(4),q2 -> D  (U1 in LDS, shared)
    {
        const int n1 = tt >> 2, m2 = (tt >> 1) & 1, m3 = tt & 1;
        float o[8];
#pragma unroll
        for (int i = 0; i < 8; ++i) o[i] = 0.f;
#pragma unroll
        for (int n2 = 0; n2 < 4; ++n2)
#pragma unroll
        for (int q2 = 0; q2 < 2; ++q2) {
            float cb[4];
#pragma unroll
            for (int m45 = 0; m45 < 4; ++m45)
                cb[m45] = smem[COS + (n1 * 4 + n2) * 17 + (m3 * 4 + m45) * 2 + q2];
#pragma unroll
            for (int q1 = 0; q1 < 2; ++q1) {
                const float w = smem[WU1 + ((q1 * 2 + m2) * 4 + n2) * 2 + q2];
#pragma unroll
                for (int m45 = 0; m45 < 4; ++m45)
                    o[m45 * 2 + q1] = fmaf(cb[m45], w, o[m45 * 2 + q1]);
            }
        }
#pragma unroll
        for (int m45 = 0; m45 < 4; ++m45)
#pragma unroll
        for (int q1 = 0; q1 < 2; ++q1)
            smem[DOS + (m2 * 8 + m3 * 4 + m45) * 17 + n1 * 2 + q1] = o[m45 * 2 + q1];
    }
    __syncthreads();

    // L2e: contract n1(8),q1 + bias + relu -> h2 (lanes 0-15 A, 32-47 B)
    if (tt < 16) {
        float o[4];
#pragma unroll
        for (int i = 0; i < 4; ++i) o[i] = 0.f;
#pragma unroll
        for (int n1 = 0; n1 < 8; ++n1)
#pragma unroll
        for (int q1 = 0; q1 < 2; ++q1) {
            const float dv = smem[DOS + tt * 17 + n1 * 2 + q1];
#pragma unroll
            for (int m1 = 0; m1 < 4; ++m1)
                o[m1] = fmaf(dv, u0[(m1 * 8 + n1) * 2 + q1], o[m1]);
        }
#pragma unroll
        for (int m1 = 0; m1 < 4; ++m1)
            smem[H2S + m1 * 16 + tt] = fmaxf(o[m1] + b2g[m1 * 16 + tt], 0.f);
    }
    __syncthreads();

    // ---- layer 3 dense (W3 32x64 from d_ws) + relu (all 64 lanes) ----
    {
        const float4* wr = (const float4*)(w3g + tt * 64);
        float sa = b3g[tt];
#pragma unroll
        for (int gg = 0; gg < 16; ++gg) {
            const float4 w4 = wr[gg];
            sa = fmaf(w4.x, smem[H2S + gg*4 + 0],
                 fmaf(w4.y, smem[H2S + gg*4 + 1],
                 fmaf(w4.z, smem[H2S + gg*4 + 2],
                 fmaf(w4.w, smem[H2S + gg*4 + 3], sa))));
        }
        smem[H3S + tt] = fmaxf(sa, 0.f);
    }
    __syncthreads();

    // ---- head: logits + log_softmax, one sample per 32-lane group ----
    {
        const float h3v = smem[H3S + tt];
        float pr0 = h3v * Wmg[tt];        // class 0
        float pr1 = h3v * Wmg[32 + tt];   // class 1
#pragma unroll
        for (int d = 16; d >= 1; d >>= 1) {
            pr0 += __shfl_xor(pr0, d);    // stays within 32-lane group
            pr1 += __shfl_xor(pr1, d);
        }
        if (tt == 0) {
            const float l0 = pr0 + blg[0];
            const float l1 = pr1 + blg[1];
            const float mm = fmaxf(l0, l1);
            const float lse = mm + logf(expf(l0 - mm) + expf(l1 - mm));
            const size_t bb = (size_t)(2 * b + sg);
            out[bb * 2 + 0] = l0 - lse;
            out[bb * 2 + 1] = l1 - lse;
        }
    }
}

extern "C" void kernel_launch(void* const* d_in, const int* in_sizes, int n_in,
                              void* d_out, int out_size, void* d_ws, size_t ws_size,
                              hipStream_t stream) {
    const float* x    = (const float*)d_in[0];
    const float* l1c0 = (const float*)d_in[1];
    const float* l1c1 = (const float*)d_in[2];
    const float* l1c2 = (const float*)d_in[3];
    const float* l1c3 = (const float*)d_in[4];
    const float* l1c4 = (const float*)d_in[5];
    const float* b1   = (const float*)d_in[6];
    const float* l2c0 = (const float*)d_in[7];
    const float* l2c1 = (const float*)d_in[8];
    const float* l2c2 = (const float*)d_in[9];
    const float* l2c3 = (const float*)d_in[10];
    const float* l2c4 = (const float*)d_in[11];
    const float* b2   = (const float*)d_in[12];
    const float* l3c0 = (const float*)d_in[13];
    const float* l3c1 = (const float*)d_in[14];
    const float* l3c2 = (const float*)d_in[15];
    const float* l3c3 = (const float*)d_in[16];
    const float* l3c4 = (const float*)d_in[17];
    const float* b3   = (const float*)d_in[18];
    const float* Wm   = (const float*)d_in[19];
    const float* bl   = (const float*)d_in[20];
    float* W3 = (float*)d_ws;  // 2048 floats scratch

    tt_setup_w3<<<8, 256, 0, stream>>>(l3c0, l3c1, l3c2, l3c3, l3c4, W3);
    tt_main<<<1024, 64, 0, stream>>>(x, l1c0, l1c1, l1c2, l1c3, l1c4, b1,
                                     l2c0, l2c1, l2c2, l2c3, l2c4, b2, b3,
                                     Wm, bl, W3, (float*)d_out);
}